// Round 13
// baseline (122.610 us; speedup 1.0000x reference)
//
#include <hip/hip_runtime.h>
#include <stdint.h>

#define NROWS 8192
#define DIM   2048
#define MARGIN 2.0f
#define SCALEQ (127.0f / 6.0f)          // quantize scale
#define S2     ((6.0f / 127.0f) * (6.0f / 127.0f))   // dequant^2

// ---- 256x256 i8 tile kernel geometry (byte units) ----
#define BT2     256
#define BKB     128                      // K-bytes (=elems) per tile-step
#define NKT     (DIM / BKB)              // 16 K-tiles
#define NT2     (NROWS / BT2)            // 32 tile-rows
#define NTILES2 (NT2 * (NT2 + 1) / 2)    // 528 upper-tri tiles
#define NQ      16                       // tiles 0..15 split into 4 row-quarters
// SINGLE-buffered LDS: A [0,32K) 256x128, B [32K,64K) 256x128 -> 2 blocks/CU
#define BOFF    32768

typedef __attribute__((ext_vector_type(4)))  int  int4v;    // 16B operand
typedef __attribute__((ext_vector_type(16))) int  int16v;   // 32x32 i32 acc
typedef unsigned char uchar;

// triangular decode (ti <= tj)
__device__ __forceinline__ void decode_tile(int bid, int* ti, int* tj) {
    float fn = (float)NT2 + 0.5f;
    int r = (int)(fn - sqrtf(fn * fn - 2.0f * (float)bid));
    if (r < 0) r = 0;
    if (r >= NT2) r = NT2 - 1;
    while ((r + 1) * NT2 - ((r + 1) * r) / 2 <= bid) ++r;
    while (r * NT2 - (r * (r - 1)) / 2 > bid) --r;
    *ti = r;
    *tj = r + (bid - (r * NT2 - (r * (r - 1)) / 2));
}

__device__ __forceinline__ uint pack4(float4 v) {
    int q0 = (int)__builtin_rintf(v.x * SCALEQ);
    int q1 = (int)__builtin_rintf(v.y * SCALEQ);
    int q2 = (int)__builtin_rintf(v.z * SCALEQ);
    int q3 = (int)__builtin_rintf(v.w * SCALEQ);
    q0 = min(max(q0, -127), 127); q1 = min(max(q1, -127), 127);
    q2 = min(max(q2, -127), 127); q3 = min(max(q3, -127), 127);
    return (uint)(q0 & 0xFF) | ((uint)(q1 & 0xFF) << 8) |
           ((uint)(q2 & 0xFF) << 16) | ((uint)(q3 & 0xFF) << 24);
}

// ---------------- kernel 1: fp32 -> i8 quantize + fp32 row sum of squares ---
__global__ __launch_bounds__(256) void prep_kernel(const float* __restrict__ p,
                                                   uchar* __restrict__ pb,
                                                   float* __restrict__ sq) {
    int row = blockIdx.x;
    int t = threadIdx.x;
    const float4* prow = (const float4*)(p + (size_t)row * DIM);
    uint* qrow = (uint*)(pb + (size_t)row * DIM);
    float4 a = prow[t];
    float4 b = prow[t + 256];
    float s = a.x * a.x + a.y * a.y + a.z * a.z + a.w * a.w
            + b.x * b.x + b.y * b.y + b.z * b.z + b.w * b.w;
    qrow[t] = pack4(a);
    qrow[t + 256] = pack4(b);
#pragma unroll
    for (int o = 32; o > 0; o >>= 1) s += __shfl_down(s, o, 64);
    __shared__ float wsums[4];
    int lane = t & 63, wvv = t >> 6;
    if (lane == 0) wsums[wvv] = s;
    __syncthreads();
    if (t == 0) sq[row] = wsums[0] + wsums[1] + wsums[2] + wsums[3];
}

// ---------------- staging: global -> LDS, linear dest, pre-swizzled src -----
// 512 threads, half-tile = 128 rows x 128B = 16KB -> 2 insts/thread.
// which: 0 = A half0, 1 = A half1, 2 = B half0, 3 = B half1, for K-tile t.
// t >= NKT clamps to NKT-1 (dead data; single buffer so parity irrelevant).
__device__ __forceinline__ void stage_ht(const uchar* __restrict__ pb,
                                         uchar* lds, int t, int which,
                                         int ibase, int jbase, int tid) {
    if (t >= NKT) t = NKT - 1;
    const int h = which & 1;
    const int row0 = ((which >= 2) ? jbase : ibase) + h * 128;
    const uchar* g0 = pb + (size_t)row0 * DIM + t * BKB;
    uchar* l0 = lds + ((which >= 2) ? BOFF : 0) + h * 16384;
#pragma unroll
    for (int r = 0; r < 2; ++r) {
        int row = r * 64 + (tid >> 3);
        int c8 = (tid & 7) ^ ((tid >> 3) & 7);         // pre-swizzled 16B slot
        const uchar* g = g0 + (size_t)row * DIM + c8 * 16;
        uchar* l = l0 + r * 8192 + (tid >> 6) * 1024;  // wave-uniform (+lane*16 HW)
        __builtin_amdgcn_global_load_lds(
            (const __attribute__((address_space(1))) uint32_t*)g,
            (__attribute__((address_space(3))) uint32_t*)l, 16, 0, 0);
    }
}

// quarter-block A stage: 64 rows x 128B = 8KB -> 1 inst/thread (512 threads)
__device__ __forceinline__ void stage_qA(const uchar* __restrict__ pb,
                                         uchar* lds, int t, int ibase, int tid) {
    if (t >= NKT) t = NKT - 1;
    const uchar* g0 = pb + (size_t)ibase * DIM + t * BKB;
    int row = tid >> 3;                                // 0..63
    int c8 = (tid & 7) ^ ((tid >> 3) & 7);
    const uchar* g = g0 + (size_t)row * DIM + c8 * 16;
    uchar* l = lds + (tid >> 6) * 1024;
    __builtin_amdgcn_global_load_lds(
        (const __attribute__((address_space(1))) uint32_t*)g,
        (__attribute__((address_space(3))) uint32_t*)l, 16, 0, 0);
}

#define BARF()   do { __builtin_amdgcn_s_barrier(); \
                      asm volatile("" ::: "memory"); } while (0)
#define WAITL()  asm volatile("s_waitcnt lgkmcnt(0)" ::: "memory")
#define WAITV0() asm volatile("s_waitcnt vmcnt(0)" ::: "memory")
#define PRIO1()  __builtin_amdgcn_s_setprio(1)
#define PRIO0()  __builtin_amdgcn_s_setprio(0)
#define SB0()    __builtin_amdgcn_sched_barrier(0)

// swizzled ds_read of 16B i8 frags: row stride 128B, slot ^= (row&7) = (lane&7)
#define READ_A(MH)                                                             \
    _Pragma("unroll") for (int mt = 0; mt < 2; ++mt)                           \
    _Pragma("unroll") for (int s = 0; s < 4; ++s) {                            \
        int rl = wr * 128 + ((MH) * 2 + mt) * 32 + (lane & 31);                \
        af[mt][s] = *(const int4v*)&lds[rl * 128 +                             \
                     (((2 * s + kh) ^ (lane & 7)) * 16)];                      \
    }

#define READ_B(NH)                                                             \
    _Pragma("unroll") for (int s = 0; s < 4; ++s) {                            \
        int rl = wc * 64 + (NH) * 32 + (lane & 31);                            \
        bf[NH][s] = *(const int4v*)&lds[BOFF + rl * 128 +                      \
                     (((2 * s + kh) ^ (lane & 7)) * 16)];                      \
    }

#define MFMA_Q(MH, NH)                                                         \
    _Pragma("unroll") for (int mt = 0; mt < 2; ++mt)                           \
    _Pragma("unroll") for (int s = 0; s < 4; ++s)                              \
        acc[(MH) * 2 + mt][NH] = __builtin_amdgcn_mfma_i32_32x32x32_i8(        \
            af[mt][s], bf[NH][s], acc[(MH) * 2 + mt][NH], 0, 0, 0);

// FULL step, SINGLE buffer, 2 barriers. Window proof:
//  - all 24 reads drain at WAITL before BAR1 -> no wave reads buffer after;
//  - stages(T+1) (same buffer) issue post-BAR1; Q(1,*) MFMAs are reg-only;
//  - WAITV0 before BAR2 -> buffer holds T+1 when any wave passes BAR2.
// With 2 blocks/CU the WAITV0 drain + read bursts hide under the co-resident
// block's MFMA phase (m97/m114 implicit overlap).
#define STEP_FULL(T)                                                           \
    {                                                                          \
        READ_A(0);                                                             \
        READ_B(0);                                                             \
        READ_B(1);                                                             \
        PRIO1(); MFMA_Q(0, 0); MFMA_Q(0, 1); PRIO0();                          \
        READ_A(1);                                                             \
        WAITL(); BARF();                                                       \
        stage_ht(pb, lds, (T) + 1, 2, ibase, jbase, tid);                      \
        stage_ht(pb, lds, (T) + 1, 3, ibase, jbase, tid);                      \
        stage_ht(pb, lds, (T) + 1, 0, ibase, jbase, tid);                      \
        stage_ht(pb, lds, (T) + 1, 1, ibase, jbase, tid);                      \
        SB0();                                                                 \
        PRIO1(); MFMA_Q(1, 0); MFMA_Q(1, 1); PRIO0();                          \
        WAITV0(); BARF();                                                      \
    }

// QUARTER step (64x256 strip; wave w owns cols w*32..w*32+31)
#define STEP_Q(T)                                                              \
    {                                                                          \
        _Pragma("unroll") for (int mt = 0; mt < 2; ++mt)                       \
        _Pragma("unroll") for (int s = 0; s < 4; ++s) {                        \
            int rl = mt * 32 + (lane & 31);                                    \
            aq[mt][s] = *(const int4v*)&lds[rl * 128 +                         \
                         (((2 * s + kh) ^ (lane & 7)) * 16)];                  \
        }                                                                      \
        _Pragma("unroll") for (int s = 0; s < 4; ++s) {                        \
            int rl = wv * 32 + (lane & 31);                                    \
            bq[s] = *(const int4v*)&lds[BOFF + rl * 128 +                      \
                     (((2 * s + kh) ^ (lane & 7)) * 16)];                      \
        }                                                                      \
        WAITL(); BARF();                                                       \
        stage_qA(pb, lds, (T) + 1, ibase, tid);                                \
        stage_ht(pb, lds, (T) + 1, 2, ibase, jbase, tid);                      \
        stage_ht(pb, lds, (T) + 1, 3, ibase, jbase, tid);                      \
        SB0();                                                                 \
        PRIO1();                                                               \
        _Pragma("unroll") for (int s = 0; s < 4; ++s)                          \
        _Pragma("unroll") for (int mt = 0; mt < 2; ++mt)                       \
            accq[mt] = __builtin_amdgcn_mfma_i32_32x32x32_i8(                  \
                aq[mt][s], bq[s], accq[mt], 0, 0, 0);                          \
        PRIO0();                                                               \
        WAITV0(); BARF();                                                      \
    }

// ---------------- kernel 2: triangular Gram + fused loss --------------------
// Grid = 64 quarter blocks (tiles 0..15 x 4 row-quarters, dispatched first)
//      + 512 full tiles. 512 threads, 8 waves; 64KB LDS -> 2 blocks/CU.
__global__ __launch_bounds__(512) void tile2_kernel(
    const uchar* __restrict__ pb, const float* __restrict__ sq,
    const int* __restrict__ gt, double* __restrict__ accum) {

    __shared__ uchar lds[65536];   // 64 KiB single buffer: A | B
    __shared__ float wsum[8];

    const int bx = (int)blockIdx.x;
    const bool is_q = (bx < 4 * NQ);
    int bid, qq = 0;
    if (is_q) { bid = bx >> 2; qq = bx & 3; }
    else { int f = bx - 4 * NQ; bid = NQ + ((f & 7) << 6) + (f >> 3); } // 512=8*64

    int ti, tj;
    decode_tile(bid, &ti, &tj);

    const int tid = threadIdx.x;
    const int lane = tid & 63;
    const int kh = lane >> 5;            // K-half within a 32-wide slice
    const int wv = tid >> 6;             // wave 0..7
    const int wr = wv >> 2;              // full: row half (128 rows)
    const int wc = wv & 3;               // full: col group (64 cols)
    const int jbase = tj * BT2;
    const int ibase = ti * BT2 + (is_q ? qq * 64 : 0);

    const float invd = 1.0f / (float)DIM;
    float lsum = 0.f;

    if (!is_q) {
        int16v acc[4][2] = {};
        int4v af[2][4];
        int4v bf[2][4];

        // prologue: stage tile 0; drain; barrier.
        stage_ht(pb, lds, 0, 2, ibase, jbase, tid);
        stage_ht(pb, lds, 0, 3, ibase, jbase, tid);
        stage_ht(pb, lds, 0, 0, ibase, jbase, tid);
        stage_ht(pb, lds, 0, 1, ibase, jbase, tid);
        WAITV0();
        BARF();

#pragma unroll 1
        for (int s0 = 0; s0 < NKT; ++s0) {
            STEP_FULL(s0);
        }

        // fused epilogue: dequant -> d2 -> contrastive term -> weighted sum
        int j0 = jbase + wc * 64 + (lane & 31);
        float sqj[2]; int gj[2];
#pragma unroll
        for (int n = 0; n < 2; ++n) { int j = j0 + n * 32; sqj[n] = sq[j]; gj[n] = gt[j]; }
        const float wb = (ti != tj) ? 2.0f : 1.0f;
#pragma unroll
        for (int mi = 0; mi < 4; ++mi) {
#pragma unroll
            for (int q = 0; q < 4; ++q) {
#pragma unroll
                for (int rr = 0; rr < 4; ++rr) {
                    int i = ibase + wr * 128 + mi * 32 + rr + 8 * q + 4 * kh;
                    float sqi = sq[i];
                    int gi = gt[i];
#pragma unroll
                    for (int n = 0; n < 2; ++n) {
                        int j = j0 + n * 32;
                        float dot = S2 * (float)acc[mi][n][q * 4 + rr];
                        float d2 = fmaxf(sqi + sqj[n] - 2.0f * dot, 0.0f) * invd;
                        float term = (gi == gj[n]) ? d2 : fmaxf(MARGIN - d2, 0.0f);
                        float w = wb;
                        if (ti == tj && i == j) w = 2.0f;
                        lsum += w * term;
                    }
                }
            }
        }
    } else {
        int16v accq[2] = {};
        int4v aq[2][4], bq[4];

        stage_qA(pb, lds, 0, ibase, tid);
        stage_ht(pb, lds, 0, 2, ibase, jbase, tid);
        stage_ht(pb, lds, 0, 3, ibase, jbase, tid);
        WAITV0();
        BARF();

#pragma unroll 1
        for (int s0 = 0; s0 < NKT; ++s0) {
            STEP_Q(s0);
        }

        int j = jbase + wv * 32 + (lane & 31);
        float sqj = sq[j];
        int gj = gt[j];
        const float wb = (ti != tj) ? 2.0f : 1.0f;
#pragma unroll
        for (int mt = 0; mt < 2; ++mt) {
#pragma unroll
            for (int q = 0; q < 4; ++q) {
#pragma unroll
                for (int rr = 0; rr < 4; ++rr) {
                    int i = ibase + mt * 32 + rr + 8 * q + 4 * kh;
                    float dot = S2 * (float)accq[mt][q * 4 + rr];
                    float d2 = fmaxf(sq[i] + sqj - 2.0f * dot, 0.0f) * invd;
                    float term = (gt[i] == gj) ? d2 : fmaxf(MARGIN - d2, 0.0f);
                    float w = wb;
                    if (ti == tj && i == j) w = 2.0f;
                    lsum += w * term;
                }
            }
        }
    }

#pragma unroll
    for (int o = 32; o > 0; o >>= 1) lsum += __shfl_down(lsum, o, 64);
    if (lane == 0) wsum[wv] = lsum;
    __syncthreads();
    if (tid == 0) {
        float s = 0.f;
#pragma unroll
        for (int w = 0; w < 8; ++w) s += wsum[w];
        atomicAdd(accum, (double)s);
    }
}

// ---------------- kernel 3: finalize ----------------------------------------
__global__ void finalize_kernel(const double* __restrict__ accum,
                                float* __restrict__ out) {
    if (threadIdx.x == 0)
        out[0] = (float)(accum[0] * (1.0 / ((double)NROWS * (double)(NROWS - 1))));
}

extern "C" void kernel_launch(void* const* d_in, const int* in_sizes, int n_in,
                              void* d_out, int out_size, void* d_ws, size_t ws_size,
                              hipStream_t stream) {
    (void)in_sizes; (void)n_in; (void)out_size; (void)ws_size;
    const float* p = (const float*)d_in[0];
    const int* gt = (const int*)d_in[1];
    float* out = (float*)d_out;

    // ws layout: pb 16MB i8 | sq 32KB | accum 8B
    uchar* pb = (uchar*)d_ws;
    size_t off = (size_t)NROWS * DIM;                   // 16,777,216
    float* sq = (float*)((char*)d_ws + off);
    off += (size_t)NROWS * sizeof(float);               // +32 KB
    double* accum = (double*)((char*)d_ws + off);

    (void)hipMemsetAsync(accum, 0, sizeof(double), stream);
    prep_kernel<<<NROWS, 256, 0, stream>>>(p, pb, sq);
    tile2_kernel<<<4 * NQ + 512, 512, 0, stream>>>(pb, sq, gt, accum);
    finalize_kernel<<<1, 64, 0, stream>>>(accum, out);
}

// Round 14
// 114.189 us; speedup vs baseline: 1.0737x; 1.0737x over previous
//
#include <hip/hip_runtime.h>
#include <stdint.h>

#define NROWS 8192
#define DIM   2048
#define MARGIN 2.0f
#define SCALEQ (127.0f / 6.0f)          // quantize scale
#define S2     ((6.0f / 127.0f) * (6.0f / 127.0f))   // dequant^2

// ---- 128x128 i8 tile kernel geometry (byte units) ----
#define BT      128
#define BKB     128                      // K-bytes (=elems) per tile-step
#define NKT     (DIM / BKB)              // 16 K-tiles
#define NTR     (NROWS / BT)             // 64 tile-rows
#define NTILES  (NTR * (NTR + 1) / 2)    // 2080 upper-tri tiles (= 8 * 260)
// SINGLE-buffered LDS: A [0,16K) 128x128B, B [16K,32K) 128x128B
#define BOFF    16384

typedef __attribute__((ext_vector_type(4)))  int  int4v;    // 16B operand
typedef __attribute__((ext_vector_type(16))) int  int16v;   // 32x32 i32 acc
typedef unsigned char uchar;

// triangular decode (ti <= tj) at 128-granularity
__device__ __forceinline__ void decode_tile(int bid, int* ti, int* tj) {
    float fn = (float)NTR + 0.5f;
    int r = (int)(fn - sqrtf(fn * fn - 2.0f * (float)bid));
    if (r < 0) r = 0;
    if (r >= NTR) r = NTR - 1;
    while ((r + 1) * NTR - ((r + 1) * r) / 2 <= bid) ++r;
    while (r * NTR - (r * (r - 1)) / 2 > bid) --r;
    *ti = r;
    *tj = r + (bid - (r * NTR - (r * (r - 1)) / 2));
}

__device__ __forceinline__ uint pack4(float4 v) {
    int q0 = (int)__builtin_rintf(v.x * SCALEQ);
    int q1 = (int)__builtin_rintf(v.y * SCALEQ);
    int q2 = (int)__builtin_rintf(v.z * SCALEQ);
    int q3 = (int)__builtin_rintf(v.w * SCALEQ);
    q0 = min(max(q0, -127), 127); q1 = min(max(q1, -127), 127);
    q2 = min(max(q2, -127), 127); q3 = min(max(q3, -127), 127);
    return (uint)(q0 & 0xFF) | ((uint)(q1 & 0xFF) << 8) |
           ((uint)(q2 & 0xFF) << 16) | ((uint)(q3 & 0xFF) << 24);
}

// ---------------- kernel 1: fp32 -> i8 quantize + fp32 row sum of squares ---
// sq from the fp32 ORIGINALS: cancels the quantization distance-inflation bias.
__global__ __launch_bounds__(256) void prep_kernel(const float* __restrict__ p,
                                                   uchar* __restrict__ pb,
                                                   float* __restrict__ sq) {
    int row = blockIdx.x;
    int t = threadIdx.x;
    const float4* prow = (const float4*)(p + (size_t)row * DIM);
    uint* qrow = (uint*)(pb + (size_t)row * DIM);
    float4 a = prow[t];
    float4 b = prow[t + 256];
    float s = a.x * a.x + a.y * a.y + a.z * a.z + a.w * a.w
            + b.x * b.x + b.y * b.y + b.z * b.z + b.w * b.w;
    qrow[t] = pack4(a);
    qrow[t + 256] = pack4(b);
#pragma unroll
    for (int o = 32; o > 0; o >>= 1) s += __shfl_down(s, o, 64);
    __shared__ float wsums[4];
    int lane = t & 63, wvv = t >> 6;
    if (lane == 0) wsums[wvv] = s;
    __syncthreads();
    if (t == 0) sq[row] = wsums[0] + wsums[1] + wsums[2] + wsums[3];
}

// ---------------- staging: global -> LDS, linear dest, pre-swizzled src -----
// 256 threads, region = 128 rows x 128B = 16KB -> 4 insts/thread.
// t >= NKT clamps to NKT-1 (dead data; single buffer, window-safe).
__device__ __forceinline__ void stage_m(const uchar* __restrict__ pb,
                                        uchar* lds, int t, int isB,
                                        int rbase, int tid) {
    if (t >= NKT) t = NKT - 1;
    const uchar* g0 = pb + (size_t)rbase * DIM + t * BKB;
    uchar* l0 = lds + (isB ? BOFF : 0);
#pragma unroll
    for (int r = 0; r < 4; ++r) {
        int row = r * 32 + (tid >> 3);
        int c8 = (tid & 7) ^ ((tid >> 3) & 7);         // pre-swizzled 16B slot
        const uchar* g = g0 + (size_t)row * DIM + c8 * 16;
        uchar* l = l0 + r * 4096 + (tid >> 6) * 1024;  // wave-uniform (+lane*16 HW)
        __builtin_amdgcn_global_load_lds(
            (const __attribute__((address_space(1))) uint32_t*)g,
            (__attribute__((address_space(3))) uint32_t*)l, 16, 0, 0);
    }
}

#define BARF()   do { __builtin_amdgcn_s_barrier(); \
                      asm volatile("" ::: "memory"); } while (0)
#define WAITL()  asm volatile("s_waitcnt lgkmcnt(0)" ::: "memory")
#define WAITV0() asm volatile("s_waitcnt vmcnt(0)" ::: "memory")
#define PRIO1()  __builtin_amdgcn_s_setprio(1)
#define PRIO0()  __builtin_amdgcn_s_setprio(0)
#define SB0()    __builtin_amdgcn_sched_barrier(0)

// swizzled ds_read of 16B i8 frags: row stride 128B, slot ^= (row&7) = (lane&7)
#define READ_A(MT)                                                             \
    _Pragma("unroll") for (int s = 0; s < 4; ++s) {                            \
        int rl = wr * 64 + (MT) * 32 + (lane & 31);                            \
        af[MT][s] = *(const int4v*)&lds[rl * 128 +                             \
                     (((2 * s + kh) ^ (lane & 7)) * 16)];                      \
    }

#define READ_B(NT)                                                             \
    _Pragma("unroll") for (int s = 0; s < 4; ++s) {                            \
        int rl = wc * 64 + (NT) * 32 + (lane & 31);                            \
        bf[NT][s] = *(const int4v*)&lds[BOFF + rl * 128 +                      \
                     (((2 * s + kh) ^ (lane & 7)) * 16)];                      \
    }

#define MFMA_ROW(MT)                                                           \
    _Pragma("unroll") for (int s = 0; s < 4; ++s)                              \
    _Pragma("unroll") for (int nt = 0; nt < 2; ++nt)                           \
        acc[MT][nt] = __builtin_amdgcn_mfma_i32_32x32x32_i8(                   \
            af[MT][s], bf[nt][s], acc[MT][nt], 0, 0, 0);

// Step, SINGLE buffer, 2 barriers. Window proof:
//  - all 16 reads drain at WAITL before BAR1 -> no wave reads buffer after;
//  - stages(T+1) (same buffer) issue post-BAR1; mt=1 MFMAs are reg-only;
//  - WAITV0 before BAR2 -> buffer holds T+1 when any wave passes BAR2.
// Cross-block overlap: the co-resident independent block's MFMA phase hides
// this block's read burst and stage drain (m114 mechanism).
#define STEP(T)                                                                \
    {                                                                          \
        READ_A(0);                                                             \
        READ_B(0);                                                             \
        READ_B(1);                                                             \
        PRIO1(); MFMA_ROW(0); PRIO0();                                         \
        READ_A(1);                                                             \
        WAITL(); BARF();                                                       \
        stage_m(pb, lds, (T) + 1, 0, ibase, tid);                              \
        stage_m(pb, lds, (T) + 1, 1, jbase, tid);                              \
        SB0();                                                                 \
        PRIO1(); MFMA_ROW(1); PRIO0();                                         \
        WAITV0(); BARF();                                                      \
    }

// ---------------- kernel 2: 128² triangular Gram + fused loss ---------------
// Grid = 2080 tiles, 256 threads (4 waves). ~180 regs/wave (mid 128-255 band)
// -> 8 waves/CU = TWO independent co-resident blocks.
__global__ __launch_bounds__(256) void tile2_kernel(
    const uchar* __restrict__ pb, const float* __restrict__ sq,
    const int* __restrict__ gt, double* __restrict__ accum) {

    __shared__ uchar lds[32768];   // 32 KiB single buffer: A | B
    __shared__ float wsum[4];

    int f = (int)blockIdx.x;
    int bid = (f & 7) * (NTILES / 8) + (f >> 3);   // bijective (2080 = 8*260)

    int ti, tj;
    decode_tile(bid, &ti, &tj);

    const int tid = threadIdx.x;
    const int lane = tid & 63;
    const int kh = lane >> 5;            // K-half within a 32-wide slice
    const int wv = tid >> 6;             // wave 0..3
    const int wr = wv >> 1;              // row half (64 rows)
    const int wc = wv & 1;               // col half (64 cols)
    const int ibase = ti * BT;
    const int jbase = tj * BT;

    int16v acc[2][2] = {};               // 64 AGPR
    int4v af[2][4];                      // 32 VGPR
    int4v bf[2][4];                      // 32 VGPR

    // prologue: stage tile 0 (8 issues); drain; barrier.
    stage_m(pb, lds, 0, 0, ibase, tid);
    stage_m(pb, lds, 0, 1, jbase, tid);
    WAITV0();
    BARF();

#pragma unroll 1
    for (int s0 = 0; s0 < NKT; ++s0) {
        STEP(s0);
    }

    // fused epilogue: dequant -> d2 -> contrastive term -> weighted sum
    const float invd = 1.0f / (float)DIM;
    float lsum = 0.f;
    {
        int j0 = jbase + wc * 64 + (lane & 31);
        float sqj[2]; int gj[2];
#pragma unroll
        for (int nt = 0; nt < 2; ++nt) { int j = j0 + nt * 32; sqj[nt] = sq[j]; gj[nt] = gt[j]; }
        const float wb = (ti != tj) ? 2.0f : 1.0f;
#pragma unroll
        for (int mt = 0; mt < 2; ++mt) {
#pragma unroll
            for (int q = 0; q < 4; ++q) {
#pragma unroll
                for (int rr = 0; rr < 4; ++rr) {
                    int i = ibase + wr * 64 + mt * 32 + rr + 8 * q + 4 * kh;
                    float sqi = sq[i];
                    int gi = gt[i];
#pragma unroll
                    for (int nt = 0; nt < 2; ++nt) {
                        int j = j0 + nt * 32;
                        float dot = S2 * (float)acc[mt][nt][q * 4 + rr];
                        float d2 = fmaxf(sqi + sqj[nt] - 2.0f * dot, 0.0f) * invd;
                        float term = (gi == gj[nt]) ? d2 : fmaxf(MARGIN - d2, 0.0f);
                        float w = wb;
                        if (ti == tj && i == j) w = 2.0f;   // triu diagonal once*2
                        lsum += w * term;
                    }
                }
            }
        }
    }

#pragma unroll
    for (int o = 32; o > 0; o >>= 1) lsum += __shfl_down(lsum, o, 64);
    if (lane == 0) wsum[wv] = lsum;
    __syncthreads();
    if (tid == 0)
        atomicAdd(accum, (double)(wsum[0] + wsum[1] + wsum[2] + wsum[3]));
}

// ---------------- kernel 3: finalize ----------------------------------------
__global__ void finalize_kernel(const double* __restrict__ accum,
                                float* __restrict__ out) {
    if (threadIdx.x == 0)
        out[0] = (float)(accum[0] * (1.0 / ((double)NROWS * (double)(NROWS - 1))));
}

extern "C" void kernel_launch(void* const* d_in, const int* in_sizes, int n_in,
                              void* d_out, int out_size, void* d_ws, size_t ws_size,
                              hipStream_t stream) {
    (void)in_sizes; (void)n_in; (void)out_size; (void)ws_size;
    const float* p = (const float*)d_in[0];
    const int* gt = (const int*)d_in[1];
    float* out = (float*)d_out;

    // ws layout: pb 16MB i8 | sq 32KB | accum 8B
    uchar* pb = (uchar*)d_ws;
    size_t off = (size_t)NROWS * DIM;                   // 16,777,216
    float* sq = (float*)((char*)d_ws + off);
    off += (size_t)NROWS * sizeof(float);               // +32 KB
    double* accum = (double*)((char*)d_ws + off);

    (void)hipMemsetAsync(accum, 0, sizeof(double), stream);
    prep_kernel<<<NROWS, 256, 0, stream>>>(p, pb, sq);
    tile2_kernel<<<NTILES, 256, 0, stream>>>(pb, sq, gt, accum);
    finalize_kernel<<<1, 64, 0, stream>>>(accum, out);
}